// Round 1
// 1224.528 us; speedup vs baseline: 1.2271x; 1.2271x over previous
//
#include <hip/hip_runtime.h>
#include <hip/hip_fp16.h>

// Problem constants
#define K_DIM   4096
#define N_DIM   11008
#define M_DIM   8192
#define NGROUPS 32            // K_DIM / 128

// 256^2 8-phase template geometry (learn_hip m194-m201 structure)
#define BM 256
#define BN 256
#define BK 64
#define NT (K_DIM / BK)       // 64 K-tiles, even -> 2 tiles per loop iter

typedef __bf16 bf16x8 __attribute__((ext_vector_type(8)));
typedef float  f32x4  __attribute__((ext_vector_type(4)));

#define GAS __attribute__((address_space(1)))
#define LAS __attribute__((address_space(3)))

__device__ __forceinline__ unsigned short f2bf(float f) {
    unsigned int u = __float_as_uint(f);
    u += 0x7fffu + ((u >> 16) & 1u);   // RNE
    return (unsigned short)(u >> 16);
}

// ---- prep: x fp32 -> bf16 bits ----
__global__ void prep_x_kernel(const float4* __restrict__ x, ushort4* __restrict__ xb, int nq) {
    int stride = gridDim.x * blockDim.x;
    for (int i = blockIdx.x * blockDim.x + threadIdx.x; i < nq; i += stride) {
        float4 v = x[i];
        ushort4 o;
        o.x = f2bf(v.x); o.y = f2bf(v.y); o.z = f2bf(v.z); o.w = f2bf(v.w);
        xb[i] = o;
    }
}

// ---- prep: W dequant int32 * fp32-scale -> bf16 bits ----
// scales arrive upcast to float32 from the harness (fp16 not shipped).
__global__ void prep_w_kernel(const int4* __restrict__ q, const float* __restrict__ sc,
                              ushort4* __restrict__ wb, int nq) {
    int stride = gridDim.x * blockDim.x;
    for (int i = blockIdx.x * blockDim.x + threadIdx.x; i < nq; i += stride) {
        int4 v = q[i];
        int o = i >> 10;             // K_DIM/4 = 1024 quads per output row
        int g = (i & 1023) >> 5;     // 128/4 = 32 quads per group
        float s = sc[(o << 5) + g];
        ushort4 w;
        w.x = f2bf((float)v.x * s);
        w.y = f2bf((float)v.y * s);
        w.z = f2bf((float)v.z * s);
        w.w = f2bf((float)v.w * s);
        wb[i] = w;
    }
}

// =====================================================================
// 256x256x64 8-phase GEMM, counted-vmcnt pipeline (T1+T2+T3+T4+T5).
//
// C[M,N] = A[M,K] * B[N,K]^T + bias ; A,B bf16-bit ushort, K contiguous.
//
// 512 threads = 8 waves (wr in {0,1} x wc in {0..3}); per-wave C tile
// 128x64 = acc[8][4] f32x4 fragments of 16x16.
//
// LDS (static 128 KiB): [A buf0 | A buf1 | B buf0 | B buf1], each
// 256x64 bf16 = 32 KiB. 16B-granule XOR swizzle g' = g ^ (row&7)
// (pre-swizzled GLOBAL source so global_load_lds's linear wave-uniform
// dest constraint holds; ds_read_b128 fragments land 2-way/bank = free;
// measured 0 bank conflicts with this scheme at 128^2).
//
// Half-tile = 128 rows x 64 cols = 16 KiB = 2 global_load_lds rounds of
// 512thr x 16B. Region order per tile: h0=Ah0(rows0-127), h1=Ah1,
// h2=Bh0(N rows 0-127), h3=Bh1.
//
// Phase read schedule (per K-tile, 4 phases): ph1: ALL 16 A-frags + B n0
// (18 ds_read_b128); ph2: B n1 (2); ph3: B n2+n3 (4); ph4: none.
// => consumption-complete: Ah0,Ah1 mid-ph1; Bh0,Bh1 mid-ph3.
//
// Staging stream (one half-tile per phase), with tiles t,t+1 computed:
//   ph1: (t+1)h3   [Bh1 of other buf: consumed prev-iter ph7]      OK
//   ph2: (t+2)h0   [Ah0 of live buf: consumed ph1]                 OK
//   ph3: (t+2)h1   [Ah1: consumed ph1]                             OK
//   ph4: (t+2)h2 + vmcnt(6)  [Bh0: consumed ph3]                   OK
//   ph5: (t+2)h3   [Bh1: consumed ph3]                             OK
//   ph6: (t+3)h0   [Ah0 of buf1: consumed ph5]                     OK
//   ph7: (t+3)h1   [Ah1: consumed ph5]                             OK
//   ph8: (t+3)h2 + vmcnt(6)  [Bh0: consumed ph7]                   OK
// vmcnt(6)@ph4: outstanding = (t+2)h0..h2 -> tile t+1 fully landed
// before ph5 reads it. vmcnt(6)@ph8: tile t+2 landed for next iter.
// Prologue: stage t0 h0-h3, vmcnt(4), stage t1 h0-h2, vmcnt(6), barrier.
// Last iter wraps t+2/t+3 to tiles 0/1 (dummy but in-bounds; same
// region ordering => race-free, data unread).
// =====================================================================

#define FENCE()     asm volatile("" ::: "memory")
#define BARRIER()   do { FENCE(); __builtin_amdgcn_s_barrier(); FENCE(); } while (0)
#define WAITLGKM0() asm volatile("s_waitcnt lgkmcnt(0)" ::: "memory")
#define WAITVM(n)   asm volatile("s_waitcnt vmcnt(" #n ")" ::: "memory")

#define STAGE(T, H) do {                                                          \
    const int _b = (T) & 1;                                                       \
    const ushort* _src;                                                           \
    ushort* _dst;                                                                 \
    if ((H) < 2) {                                                                \
        _src = Abase + (size_t)(H) * 128 * K_DIM + (size_t)(T) * BK;              \
        _dst = &smem[_b * 16384 + (H) * 8192];                                    \
    } else {                                                                      \
        _src = Bbase + (size_t)((H) - 2) * 128 * K_DIM + (size_t)(T) * BK;        \
        _dst = &smem[32768 + _b * 16384 + ((H) - 2) * 8192];                      \
    }                                                                             \
    __builtin_amdgcn_global_load_lds((GAS const void*)(_src + go0),               \
                                     (LAS void*)(_dst + lds_u), 16, 0, 0);        \
    __builtin_amdgcn_global_load_lds((GAS const void*)(_src + go1),               \
                                     (LAS void*)(_dst + 4096 + lds_u), 16, 0, 0); \
} while (0)

#define READ_A(ABASE) do {                                                        \
    _Pragma("unroll")                                                             \
    for (int _i = 0; _i < 8; ++_i) {                                              \
        af[_i][0] = *(const bf16x8*)&smem[(ABASE) + aA + _i * 1024 + gsw0];       \
        af[_i][1] = *(const bf16x8*)&smem[(ABASE) + aA + _i * 1024 + gsw1];       \
    }                                                                             \
} while (0)

#define READ_B(BBASE, J, BJ) do {                                                 \
    BJ[0] = *(const bf16x8*)&smem[(BBASE) + bB + (J) * 1024 + gsw0];              \
    BJ[1] = *(const bf16x8*)&smem[(BBASE) + bB + (J) * 1024 + gsw1];              \
} while (0)

#define PHASE_MFMA(J, BJ) do {                                                    \
    __builtin_amdgcn_s_setprio(1);                                                \
    _Pragma("unroll")                                                             \
    for (int _ks = 0; _ks < 2; ++_ks) {                                           \
        _Pragma("unroll")                                                         \
        for (int _i = 0; _i < 8; ++_i)                                            \
            acc[_i][J] = __builtin_amdgcn_mfma_f32_16x16x32_bf16(                 \
                af[_i][_ks], BJ[_ks], acc[_i][J], 0, 0, 0);                       \
    }                                                                             \
    __builtin_amdgcn_s_setprio(0);                                                \
} while (0)

__global__ __launch_bounds__(512, 2)
void gemm_bf16_256(const ushort* __restrict__ A, const ushort* __restrict__ B,
                   const float* __restrict__ bias, float* __restrict__ C) {
    __shared__ __align__(16) ushort smem[65536];   // 128 KiB

    const int tid  = threadIdx.x;
    const int lane = tid & 63;
    const int wid  = tid >> 6;       // 0..7
    const int wr   = wid >> 2;       // 0..1 (M)
    const int wc   = wid & 3;        // 0..3 (N)

    // T1: bijective XCD swizzle (1376 % 8 == 0). XCD k gets 172 contiguous
    // logical tiles; bm fastest => 32-tile runs share one B panel (L2).
    const int bid  = blockIdx.x;
    const int wgid = (bid & 7) * 172 + (bid >> 3);
    const int bm   = wgid & 31;      // 0..31
    const int bn   = wgid >> 5;      // 0..42

    const ushort* Abase = A + (size_t)bm * BM * K_DIM;
    const ushort* Bbase = B + (size_t)bn * BN * K_DIM;

    // Staging map: issue q covers slots [q*512, q*512+512), slot s = q*512+tid
    // -> tile row = s>>3, LDS granule g' = s&7, global granule g = g'^(row&7).
    const int r0  = tid >> 3;
    const int go0 = r0 * K_DIM + ((tid & 7) ^ (r0 & 7)) * 8;
    const int s1  = 512 + tid;
    const int r1  = s1 >> 3;
    const int go1 = r1 * K_DIM + ((s1 & 7) ^ (r1 & 7)) * 8;
    const int lds_u = (tid & ~63) * 8;   // wave-uniform LDS element base

    // Fragment read addressing (row&7 == lane&7 since bases are mult of 8)
    const int aA   = (wr * 128 + (lane & 15)) * 64;
    const int bB   = (wc * 64  + (lane & 15)) * 64;
    const int gsw0 = (((lane >> 4))     ^ (lane & 7)) * 8;
    const int gsw1 = (((lane >> 4) + 4) ^ (lane & 7)) * 8;

    f32x4 acc[8][4];
#pragma unroll
    for (int i = 0; i < 8; ++i)
#pragma unroll
        for (int j = 0; j < 4; ++j) {
            acc[i][j][0] = 0.f; acc[i][j][1] = 0.f;
            acc[i][j][2] = 0.f; acc[i][j][3] = 0.f;
        }

    bf16x8 af[8][2];
    bf16x8 b0[2], b1[2], b2[2], b3[2];

    // ---- prologue: 4 + 3 half-tiles ----
    STAGE(0, 0); STAGE(0, 1); STAGE(0, 2); STAGE(0, 3);
    WAITVM(4);
    STAGE(1, 0); STAGE(1, 1); STAGE(1, 2);
    WAITVM(6);                 // tile 0 fully landed; 3 half-tiles in flight
    BARRIER();

    for (int t = 0; t < NT; t += 2) {
        int t2 = t + 2; if (t2 >= NT) t2 = 0;   // wrap: dummy, in-bounds, race-free
        int t3 = t + 3; if (t3 >= NT) t3 = 1;

        // ======== K-tile t (buffer 0: A@0, B@32768) ========
        // ph1
        READ_A(0);
        READ_B(32768, 0, b0);
        STAGE(t + 1, 3);
        BARRIER(); WAITLGKM0();
        PHASE_MFMA(0, b0);
        BARRIER();
        // ph2
        READ_B(32768, 1, b1);
        STAGE(t2, 0);
        BARRIER(); WAITLGKM0();
        PHASE_MFMA(1, b1);
        BARRIER();
        // ph3
        READ_B(32768, 2, b2);
        READ_B(32768, 3, b3);
        STAGE(t2, 1);
        BARRIER(); WAITLGKM0();
        PHASE_MFMA(2, b2);
        BARRIER();
        // ph4
        STAGE(t2, 2);
        WAITVM(6);             // tile t+1 fully landed for ph5..ph8
        BARRIER();
        PHASE_MFMA(3, b3);
        BARRIER();

        // ======== K-tile t+1 (buffer 1: A@16384, B@49152) ========
        // ph5
        READ_A(16384);
        READ_B(49152, 0, b0);
        STAGE(t2, 3);
        BARRIER(); WAITLGKM0();
        PHASE_MFMA(0, b0);
        BARRIER();
        // ph6
        READ_B(49152, 1, b1);
        STAGE(t3, 0);
        BARRIER(); WAITLGKM0();
        PHASE_MFMA(1, b1);
        BARRIER();
        // ph7
        READ_B(49152, 2, b2);
        READ_B(49152, 3, b3);
        STAGE(t3, 1);
        BARRIER(); WAITLGKM0();
        PHASE_MFMA(2, b2);
        BARRIER();
        // ph8
        STAGE(t3, 2);
        WAITVM(6);             // tile t+2 fully landed for next iter
        BARRIER();
        PHASE_MFMA(3, b3);
        BARRIER();
    }

    // drain in-flight LDS-DMA before wave exit (LDS dealloc safety)
    WAITVM(0);

    // epilogue: D layout (m89-verified): col(n) = lane&15, row(m) = (lane>>4)*4 + r
    const int col_l = lane & 15;
    const int row_l = (lane >> 4) * 4;
#pragma unroll
    for (int j = 0; j < 4; ++j) {
        int gcol = bn * BN + wc * 64 + j * 16 + col_l;
        float bv = bias[gcol];
#pragma unroll
        for (int i = 0; i < 8; ++i) {
            int grow0 = bm * BM + wr * 128 + i * 16 + row_l;
#pragma unroll
            for (int r = 0; r < 4; ++r) {
                C[(size_t)(grow0 + r) * N_DIM + gcol] = acc[i][j][r] + bv;
            }
        }
    }
}

// ---- correctness fallback if ws too small (should never run) ----
__global__ void naive_kernel(const float* __restrict__ x, const int* __restrict__ q,
                             const float* __restrict__ sc, const float* __restrict__ b,
                             float* __restrict__ out) {
    size_t idx = (size_t)blockIdx.x * blockDim.x + threadIdx.x;
    size_t total = (size_t)M_DIM * N_DIM;
    if (idx >= total) return;
    int m = (int)(idx / N_DIM);
    int n = (int)(idx % N_DIM);
    float acc = 0.f;
    for (int g = 0; g < NGROUPS; ++g) {
        float s = sc[n * NGROUPS + g];
        float p = 0.f;
        for (int k = g * 128; k < g * 128 + 128; ++k)
            p += x[(size_t)m * K_DIM + k] * (float)q[(size_t)n * K_DIM + k];
        acc += p * s;
    }
    out[idx] = acc + b[n];
}

extern "C" void kernel_launch(void* const* d_in, const int* in_sizes, int n_in,
                              void* d_out, int out_size, void* d_ws, size_t ws_size,
                              hipStream_t stream) {
    const float* x  = (const float*)d_in[0];
    const int*   wq = (const int*)d_in[1];
    const float* sc = (const float*)d_in[2];   // fp16 in reference -> fp32 from harness
    const float* bs = (const float*)d_in[3];
    float* out = (float*)d_out;

    const size_t xb_bytes = (size_t)M_DIM * K_DIM * 2;   // 67,108,864
    const size_t wb_bytes = (size_t)N_DIM * K_DIM * 2;   // 90,177,536

    if (ws_size < xb_bytes + wb_bytes) {
        size_t total = (size_t)M_DIM * N_DIM;
        int blocks = (int)((total + 255) / 256);
        naive_kernel<<<blocks, 256, 0, stream>>>(x, wq, sc, bs, out);
        return;
    }

    ushort* xb = (ushort*)d_ws;
    ushort* wb = (ushort*)((char*)d_ws + xb_bytes);

    int nq_x = M_DIM * K_DIM / 4;   // 8,388,608
    int nq_w = N_DIM * K_DIM / 4;   // 11,272,192
    prep_x_kernel<<<4096, 256, 0, stream>>>((const float4*)x, (ushort4*)xb, nq_x);
    prep_w_kernel<<<8192, 256, 0, stream>>>((const int4*)wq, sc, (ushort4*)wb, nq_w);

    dim3 grid((N_DIM / BN) * (M_DIM / BM));   // 43 * 32 = 1376
    gemm_bf16_256<<<grid, 512, 0, stream>>>(xb, wb, bs, out);
}